// Round 4
// baseline (505.850 us; speedup 1.0000x reference)
//
#include <hip/hip_runtime.h>

typedef unsigned short u16;
typedef unsigned int u32;
typedef __attribute__((ext_vector_type(8))) short short8;
typedef __attribute__((ext_vector_type(16))) float f32x16;

// ---------- bf16 helpers (RNE) ----------
__device__ __forceinline__ u16 f2bf(float f) {
    u32 u = __float_as_uint(f);
    u32 r = (u + 0x7fffu + ((u >> 16) & 1u)) >> 16;
    return (u16)r;
}
__device__ __forceinline__ float bf2f(u16 h) {
    return __uint_as_float(((u32)h) << 16);
}

// ---------- async global->LDS, 16B per lane (dst = wave-uniform base + lane*16) ----------
__device__ __forceinline__ void gld16(u16* lds_dst, const u16* g_src) {
    __builtin_amdgcn_global_load_lds(
        (const __attribute__((address_space(1))) unsigned int*)g_src,
        (__attribute__((address_space(3))) unsigned int*)lds_dst,
        16, 0, 0);
}

// =====================================================================
// split_x: fp32 [8192*1024] -> bf16 hi/lo
// =====================================================================
__global__ void split_x_k(const float* __restrict__ x, u16* __restrict__ xh,
                          u16* __restrict__ xl) {
    long i = ((long)blockIdx.x * 256 + threadIdx.x) * 4;
    float4 f = *(const float4*)(x + i);
    u16 h0 = f2bf(f.x), h1 = f2bf(f.y), h2 = f2bf(f.z), h3 = f2bf(f.w);
    u16 l0 = f2bf(f.x - bf2f(h0)), l1 = f2bf(f.y - bf2f(h1));
    u16 l2 = f2bf(f.z - bf2f(h2)), l3 = f2bf(f.w - bf2f(h3));
    uint2 hv, lv;
    hv.x = (u32)h0 | ((u32)h1 << 16); hv.y = (u32)h2 | ((u32)h3 << 16);
    lv.x = (u32)l0 | ((u32)l1 << 16); lv.y = (u32)l2 | ((u32)l3 << 16);
    *(uint2*)(xh + i) = hv;
    *(uint2*)(xl + i) = lv;
}

// =====================================================================
// splitT_w: W[k][n] fp32 (1024x1024, z in 0..2) -> Wt[n][k] bf16 hi/lo
// =====================================================================
__global__ void splitT_w_k(const float* __restrict__ Wq, const float* __restrict__ Wk,
                           const float* __restrict__ Wv, u16* __restrict__ wth,
                           u16* __restrict__ wtl) {
    __shared__ float tile[32][33];
    int z = blockIdx.z;
    const float* W = (z == 0) ? Wq : (z == 1) ? Wk : Wv;
    int n0 = blockIdx.x * 32, k0 = blockIdx.y * 32;
    int tx = threadIdx.x, ty = threadIdx.y;
#pragma unroll
    for (int r0 = 0; r0 < 4; ++r0) {
        int r = ty + r0 * 8;
        tile[r][tx] = W[(long)(k0 + r) * 1024 + n0 + tx];
    }
    __syncthreads();
    long zoff = (long)z * 1024 * 1024;
#pragma unroll
    for (int r0 = 0; r0 < 4; ++r0) {
        int r = ty + r0 * 8;
        float f = tile[tx][r];
        u16 h = f2bf(f), l = f2bf(f - bf2f(h));
        long idx = zoff + (long)(n0 + r) * 1024 + k0 + tx;
        wth[idx] = h;
        wtl[idx] = l;
    }
}

// =====================================================================
// transpose_v: v hi/lo [B*2048][1024] -> vt hi/lo per-batch [1024][2048]
// =====================================================================
__global__ void transpose_v_k(const u16* __restrict__ vh, const u16* __restrict__ vl,
                              u16* __restrict__ vth, u16* __restrict__ vtl) {
    __shared__ u16 th[32][33];
    __shared__ u16 tl[32][33];
    int z = blockIdx.z;
    int d0 = blockIdx.x * 32, s0 = blockIdx.y * 32;
    int tx = threadIdx.x, ty = threadIdx.y;
#pragma unroll
    for (int r0 = 0; r0 < 4; ++r0) {
        int r = ty + r0 * 8;
        long idx = ((long)z * 2048 + s0 + r) * 1024 + d0 + tx;
        th[r][tx] = vh[idx];
        tl[r][tx] = vl[idx];
    }
    __syncthreads();
    long zoff = (long)z * 1024 * 2048;
#pragma unroll
    for (int r0 = 0; r0 < 4; ++r0) {
        int r = ty + r0 * 8;
        long idx = zoff + (long)(d0 + r) * 2048 + s0 + tx;
        vth[idx] = th[tx][r];
        vtl[idx] = tl[tx][r];
    }
}

// =====================================================================
// GEMM: C = A * B^T, 3-term bf16 hi/lo split (fp32-accurate).
// R4: mfma_f32_32x32x16_bf16 (pipe 2382 vs 2075 TF; half the MFMA instrs).
// 512 threads = 8 waves (2 M-rows x 4 N-cols). Tile 128 x BN.
//   BN=256 (proj): per-wave 64x64 = 2x2 frags of 32x32
//   BN=128 (qk/pv): per-wave 64x32 = 2x1 frags
// BK=32 (2 k-subs of 16), ring-3 LDS, depth-2 prefetch, counted vmcnt
// across raw s_barrier (R2-proven schedule), XOR bank swizzle:
//   phys 16B-slot = logical_slot ^ ((row>>1)&3)  (involution; applied on
//   the pre-swizzled global SOURCE for global_load_lds and on ds_read).
//   32x32 read pattern (row=lane&31, 64B rows): 32 lanes cover all 8
//   bank-quads -> conflict-free.
// MODE 0: proj (bias, split hi/lo out, z selects q/k/v)
// MODE 1: qk   (causal block-skip bj>bi, fp32 scores)
// MODE 2: pv   (K limited to (bi+1)*4 steps, fp32 out, bi launch-reversed
//               so long blocks dispatch first — LPT balance)
// =====================================================================
template <int MODE, int BN>
__launch_bounds__(512, 2)
__global__ void gemm_k(const u16* __restrict__ Ah, const u16* __restrict__ Al, long sAz,
                       const u16* __restrict__ Bh, const u16* __restrict__ Bl, long sBz,
                       int lda, int ldb, int Ksize,
                       float* __restrict__ outF, long sCz, int ldc,
                       u16* __restrict__ oh0, u16* __restrict__ oh1, u16* __restrict__ oh2,
                       u16* __restrict__ ol0, u16* __restrict__ ol1, u16* __restrict__ ol2,
                       const float* __restrict__ b0, const float* __restrict__ b1,
                       const float* __restrict__ b2) {
    constexpr int NFR = BN / 128;            // B frags per wave (2 or 1)
    constexpr int ASZ = 4096;                // u16 per A hi (or lo) tile [128][32]
    constexpr int BSZ = BN * 32;             // u16 per B hi (or lo) tile [BN][32]
    constexpr int SLOT = 2 * ASZ + 2 * BSZ;  // u16 per ring slot
    constexpr int NLOADS = (BN == 256) ? 6 : 4;
    __shared__ u16 lds[3 * SLOT];

    const int bi = (MODE == 2) ? (gridDim.x - 1 - (int)blockIdx.x) : blockIdx.x;
    const int bj = blockIdx.y, z = blockIdx.z;
    if (MODE == 1 && bj > bi) return;  // fully-masked causal block
    int nsteps = Ksize / 32;
    if (MODE == 2) nsteps = min(nsteps, (bi + 1) * 4);

    const u16* gA_h = Ah + (long)z * sAz;
    const u16* gA_l = Al + (long)z * sAz;
    const u16* gB_h = Bh + (long)z * sBz;
    const u16* gB_l = Bl + (long)z * sBz;

    const int tid = threadIdx.x;
    const int lane = tid & 63, w = tid >> 6;
    const int wr = w >> 2, wc = w & 3;

    // ---- staging per-thread global offsets (pre-swizzled source, rule #21) ----
    const int srow = tid >> 2;                                   // LDS row 0..127
    const int ls8 = (((tid & 3) ^ ((tid >> 3) & 3)) << 3);       // swizzled k-slot * 8
    const long aoff  = ((long)bi * 128 + srow) * lda + ls8;
    const long boff0 = ((long)bj * BN + srow) * ldb + ls8;
    const long boff1 = boff0 + 128L * (long)ldb;                 // BN==256 second chunk
    const int wbase = w * 512;                                   // u16, wave-uniform

    f32x16 acc[2][NFR] = {};

    // ---- ds_read fragment addressing (32x32x16 A/B layout) ----
    const int r32 = lane & 31;          // frag row (A) / col (B)
    const int kg = (lane >> 5);         // k-group (8 elems) within K=16

    auto rdoff = [&](int row, int ks) {  // u16 offset within a [*][32] tile
        int s = ks * 2 + kg;
        return row * 32 + (((s ^ ((row >> 1) & 3))) << 3);
    };

    auto stage = [&](int slot, int step) {
        const int k0 = step * 32;
        u16* sb = lds + slot * SLOT;
        gld16(sb + wbase,                 gA_h + aoff + k0);
        gld16(sb + ASZ + wbase,           gA_l + aoff + k0);
        gld16(sb + 2 * ASZ + wbase,       gB_h + boff0 + k0);
        if constexpr (BN == 256) gld16(sb + 2 * ASZ + 4096 + wbase, gB_h + boff1 + k0);
        gld16(sb + 2 * ASZ + BSZ + wbase, gB_l + boff0 + k0);
        if constexpr (BN == 256) gld16(sb + 2 * ASZ + BSZ + 4096 + wbase, gB_l + boff1 + k0);
    };

    auto compute = [&](int slot) {
        const u16* LA = lds + slot * SLOT;
        const u16* LB = LA + 2 * ASZ;
        short8 a[2][2][2];    // [mf][ks][hl]
        short8 b[NFR][2][2];  // [nf][ks][hl]
#pragma unroll
        for (int mf = 0; mf < 2; ++mf)
#pragma unroll
            for (int ks = 0; ks < 2; ++ks) {
                int off = rdoff(wr * 64 + mf * 32 + r32, ks);
                a[mf][ks][0] = *(const short8*)(LA + off);
                a[mf][ks][1] = *(const short8*)(LA + ASZ + off);
            }
#pragma unroll
        for (int nf = 0; nf < NFR; ++nf)
#pragma unroll
            for (int ks = 0; ks < 2; ++ks) {
                int off = rdoff(wc * (NFR * 32) + nf * 32 + r32, ks);
                b[nf][ks][0] = *(const short8*)(LB + off);
                b[nf][ks][1] = *(const short8*)(LB + BSZ + off);
            }
        __builtin_amdgcn_s_setprio(1);
#pragma unroll
        for (int ks = 0; ks < 2; ++ks)
#pragma unroll
            for (int mf = 0; mf < 2; ++mf)
#pragma unroll
                for (int nf = 0; nf < NFR; ++nf) {
                    acc[mf][nf] = __builtin_amdgcn_mfma_f32_32x32x16_bf16(
                        a[mf][ks][0], b[nf][ks][0], acc[mf][nf], 0, 0, 0);
                    acc[mf][nf] = __builtin_amdgcn_mfma_f32_32x32x16_bf16(
                        a[mf][ks][0], b[nf][ks][1], acc[mf][nf], 0, 0, 0);
                    acc[mf][nf] = __builtin_amdgcn_mfma_f32_32x32x16_bf16(
                        a[mf][ks][1], b[nf][ks][0], acc[mf][nf], 0, 0, 0);
                }
        __builtin_amdgcn_s_setprio(0);
    };

    // ---- prologue: prefetch steps 0,1 ----
    stage(0, 0);
    if (nsteps > 1) stage(1, 1);

    int cs = 0, ns = 2;
    for (int h = 0; h < nsteps; ++h) {
        // wait for step h's own loads; keep step h+1's in flight (never 0 mid-loop)
        if (h + 1 < nsteps) {
            if constexpr (BN == 256) asm volatile("s_waitcnt vmcnt(6)" ::: "memory");
            else                     asm volatile("s_waitcnt vmcnt(4)" ::: "memory");
        } else {
            asm volatile("s_waitcnt vmcnt(0)" ::: "memory");
        }
        __builtin_amdgcn_s_barrier();       // all waves' slot-cs loads landed
        __builtin_amdgcn_sched_barrier(0);  // don't hoist reads above the barrier
        if (h + 2 < nsteps) stage(ns, h + 2);  // slot (h-1)%3 consumed pre-barrier
        compute(cs);
        cs = (cs == 2) ? 0 : cs + 1;
        ns = (ns == 2) ? 0 : ns + 1;
    }

    // ---- epilogue: 32x32 C/D layout col=lane&31, row=(j&3)+8*(j>>2)+4*(lane>>5) ----
    const int row0 = bi * 128 + wr * 64 + 4 * (lane >> 5);
    const int col0 = bj * BN + wc * (NFR * 32) + r32;

    if (MODE == 0) {
        const float* bias = (z == 0) ? b0 : (z == 1) ? b1 : b2;
        u16* oh = (z == 0) ? oh0 : (z == 1) ? oh1 : oh2;
        u16* ol = (z == 0) ? ol0 : (z == 1) ? ol1 : ol2;
#pragma unroll
        for (int nf = 0; nf < NFR; ++nf) {
            float bv = bias[col0 + nf * 32];
#pragma unroll
            for (int mf = 0; mf < 2; ++mf)
#pragma unroll
                for (int j = 0; j < 16; ++j) {
                    float v = acc[mf][nf][j] + bv;
                    int row = row0 + mf * 32 + (j & 3) + 8 * (j >> 2);
                    long idx = (long)row * ldc + col0 + nf * 32;
                    u16 h = f2bf(v);
                    oh[idx] = h;
                    ol[idx] = f2bf(v - bf2f(h));
                }
        }
    } else {
        float* o = outF + (long)z * sCz;
#pragma unroll
        for (int mf = 0; mf < 2; ++mf)
#pragma unroll
            for (int nf = 0; nf < NFR; ++nf)
#pragma unroll
                for (int j = 0; j < 16; ++j) {
                    int row = row0 + mf * 32 + (j & 3) + 8 * (j >> 2);
                    o[(long)row * ldc + col0 + nf * 32] = acc[mf][nf][j];
                }
    }
}

// =====================================================================
// softmax: per row i of S [batch][2048][2048]: read j<=i, scale 1/32,
// exp-normalize, write P hi/lo bf16 only for cols < ((i>>7)+1)*128
// (all that PV's K-limit ever reads; diag-block upper part zero-filled).
// =====================================================================
__global__ void softmax_k(const float* __restrict__ S, u16* __restrict__ Ph,
                          u16* __restrict__ Pl) {
    const long row = blockIdx.x;  // 0..8191
    const int i = (int)(row & 2047);
    const float* srow = S + row * 2048;
    u16* ph = Ph + row * 2048;
    u16* pl = Pl + row * 2048;
    const int t = threadIdx.x;
    const int limit = ((i >> 7) + 1) << 7;

    float v[8];
    float m = -1e30f;
#pragma unroll
    for (int j = 0; j < 8; ++j) {
        int c = j * 256 + t;
        float x = (c <= i) ? srow[c] : -1e30f;
        v[j] = x;
        m = fmaxf(m, x);
    }
#pragma unroll
    for (int off = 32; off; off >>= 1) m = fmaxf(m, __shfl_xor(m, off));
    __shared__ float redm[4], reds[4];
    if ((t & 63) == 0) redm[t >> 6] = m;
    __syncthreads();
    m = fmaxf(fmaxf(redm[0], redm[1]), fmaxf(redm[2], redm[3]));

    float p[8];
    float s = 0.f;
#pragma unroll
    for (int j = 0; j < 8; ++j) {
        int c = j * 256 + t;
        float e = (c <= i) ? __expf((v[j] - m) * 0.03125f) : 0.f;
        p[j] = e;
        s += e;
    }
#pragma unroll
    for (int off = 32; off; off >>= 1) s += __shfl_xor(s, off);
    if ((t & 63) == 0) reds[t >> 6] = s;
    __syncthreads();
    s = reds[0] + reds[1] + reds[2] + reds[3];
    const float inv = 1.f / s;
#pragma unroll
    for (int j = 0; j < 8; ++j) {
        int c = j * 256 + t;
        if (c < limit) {
            float o = p[j] * inv;
            u16 h = f2bf(o);
            ph[c] = h;
            pl[c] = f2bf(o - bf2f(h));
        }
    }
}

// =====================================================================
extern "C" void kernel_launch(void* const* d_in, const int* in_sizes, int n_in,
                              void* d_out, int out_size, void* d_ws, size_t ws_size,
                              hipStream_t stream) {
    const float* x  = (const float*)d_in[0];
    const float* Wq = (const float*)d_in[1];
    const float* bq = (const float*)d_in[2];
    const float* Wk = (const float*)d_in[3];
    const float* bk = (const float*)d_in[4];
    const float* Wv = (const float*)d_in[5];
    const float* bv = (const float*)d_in[6];
    float* out = (float*)d_out;
    char* ws = (char*)d_ws;
    const size_t MB = 1ull << 20;

    // region1 (64MB): [xs_hi xs_lo wt_hi wt_lo] during proj, then S
    u16* xs_hi = (u16*)(ws + 0 * MB);
    u16* xs_lo = (u16*)(ws + 16 * MB);
    u16* wt_hi = (u16*)(ws + 32 * MB);
    u16* wt_lo = (u16*)(ws + 38 * MB);
    float* S   = (float*)(ws + 0 * MB);  // 64MB, after proj complete
    // region2 (64MB): [q_hi q_lo k_hi k_lo] during qk, then [P_hi P_lo]
    u16* q_hi = (u16*)(ws + 64 * MB);
    u16* q_lo = (u16*)(ws + 80 * MB);
    u16* k_hi = (u16*)(ws + 96 * MB);
    u16* k_lo = (u16*)(ws + 112 * MB);
    u16* P_hi = (u16*)(ws + 64 * MB);  // 32MB, after qk complete
    u16* P_lo = (u16*)(ws + 96 * MB);  // 32MB
    // region3/4
    u16* v_hi  = (u16*)(ws + 128 * MB);
    u16* v_lo  = (u16*)(ws + 144 * MB);
    u16* vt_hi = (u16*)(ws + 160 * MB);
    u16* vt_lo = (u16*)(ws + 176 * MB);

    // 1) split x into bf16 hi/lo
    split_x_k<<<8192, 256, 0, stream>>>(x, xs_hi, xs_lo);
    // 2) transpose+split W -> Wt hi/lo ([3][1024][1024])
    splitT_w_k<<<dim3(32, 32, 3), dim3(32, 8), 0, stream>>>(Wq, Wk, Wv, wt_hi, wt_lo);
    // 3) QKV projections: [8192x1024] = x * Wt^T (+bias); tile 128x256, grid 768 = 3/CU
    gemm_k<0, 256><<<dim3(64, 4, 3), 512, 0, stream>>>(
        xs_hi, xs_lo, 0L, wt_hi, wt_lo, 1024L * 1024, 1024, 1024, 1024,
        nullptr, 0L, 1024, q_hi, k_hi, v_hi, q_lo, k_lo, v_lo, bq, bk, bv);
    // 4) transpose V per batch -> vt [1024][2048]
    transpose_v_k<<<dim3(32, 64, 4), dim3(32, 8), 0, stream>>>(v_hi, v_lo, vt_hi, vt_lo);
    // 5) scores S = Q * K^T per batch; tile 128x128, causal block-skip
    gemm_k<1, 128><<<dim3(16, 16, 4), 512, 0, stream>>>(
        q_hi, q_lo, 2048L * 1024, k_hi, k_lo, 2048L * 1024, 1024, 1024, 1024,
        S, 2048L * 2048, 2048, nullptr, nullptr, nullptr, nullptr, nullptr, nullptr,
        nullptr, nullptr, nullptr);
    // 6) causal softmax rows -> P hi/lo bf16 (zero-filled in diag block)
    softmax_k<<<8192, 256, 0, stream>>>(S, P_hi, P_lo);
    // 7) out = P * V per batch; tile 128x128, K limited to diagonal (bi reversed = LPT)
    gemm_k<2, 128><<<dim3(16, 8, 4), 512, 0, stream>>>(
        P_hi, P_lo, 2048L * 2048, vt_hi, vt_lo, 1024L * 2048, 2048, 2048, 2048,
        out, 2048L * 1024, 1024, nullptr, nullptr, nullptr, nullptr, nullptr, nullptr,
        nullptr, nullptr, nullptr);
}

// Round 5
// 443.923 us; speedup vs baseline: 1.1395x; 1.1395x over previous
//
#include <hip/hip_runtime.h>

typedef unsigned short u16;
typedef unsigned int u32;
typedef __attribute__((ext_vector_type(8))) short short8;
typedef __attribute__((ext_vector_type(4))) float f32x4;

// ---------- bf16 helpers (RNE) ----------
__device__ __forceinline__ u16 f2bf(float f) {
    u32 u = __float_as_uint(f);
    u32 r = (u + 0x7fffu + ((u >> 16) & 1u)) >> 16;
    return (u16)r;
}
__device__ __forceinline__ float bf2f(u16 h) {
    return __uint_as_float(((u32)h) << 16);
}

// ---------- async global->LDS, 16B per lane (dst = wave-uniform base + lane*16) ----------
__device__ __forceinline__ void gld16(u16* lds_dst, const u16* g_src) {
    __builtin_amdgcn_global_load_lds(
        (const __attribute__((address_space(1))) unsigned int*)g_src,
        (__attribute__((address_space(3))) unsigned int*)lds_dst,
        16, 0, 0);
}

// =====================================================================
// split_x: fp32 [8192*1024] -> bf16 hi/lo
// =====================================================================
__global__ void split_x_k(const float* __restrict__ x, u16* __restrict__ xh,
                          u16* __restrict__ xl) {
    long i = ((long)blockIdx.x * 256 + threadIdx.x) * 4;
    float4 f = *(const float4*)(x + i);
    u16 h0 = f2bf(f.x), h1 = f2bf(f.y), h2 = f2bf(f.z), h3 = f2bf(f.w);
    u16 l0 = f2bf(f.x - bf2f(h0)), l1 = f2bf(f.y - bf2f(h1));
    u16 l2 = f2bf(f.z - bf2f(h2)), l3 = f2bf(f.w - bf2f(h3));
    uint2 hv, lv;
    hv.x = (u32)h0 | ((u32)h1 << 16); hv.y = (u32)h2 | ((u32)h3 << 16);
    lv.x = (u32)l0 | ((u32)l1 << 16); lv.y = (u32)l2 | ((u32)l3 << 16);
    *(uint2*)(xh + i) = hv;
    *(uint2*)(xl + i) = lv;
}

// =====================================================================
// splitT_w: W[k][n] fp32 (1024x1024, z in 0..2) -> Wt[n][k] bf16 hi/lo
// =====================================================================
__global__ void splitT_w_k(const float* __restrict__ Wq, const float* __restrict__ Wk,
                           const float* __restrict__ Wv, u16* __restrict__ wth,
                           u16* __restrict__ wtl) {
    __shared__ float tile[32][33];
    int z = blockIdx.z;
    const float* W = (z == 0) ? Wq : (z == 1) ? Wk : Wv;
    int n0 = blockIdx.x * 32, k0 = blockIdx.y * 32;
    int tx = threadIdx.x, ty = threadIdx.y;
#pragma unroll
    for (int r0 = 0; r0 < 4; ++r0) {
        int r = ty + r0 * 8;
        tile[r][tx] = W[(long)(k0 + r) * 1024 + n0 + tx];
    }
    __syncthreads();
    long zoff = (long)z * 1024 * 1024;
#pragma unroll
    for (int r0 = 0; r0 < 4; ++r0) {
        int r = ty + r0 * 8;
        float f = tile[tx][r];
        u16 h = f2bf(f), l = f2bf(f - bf2f(h));
        long idx = zoff + (long)(n0 + r) * 1024 + k0 + tx;
        wth[idx] = h;
        wtl[idx] = l;
    }
}

// =====================================================================
// transpose_v: v hi/lo [B*2048][1024] -> vt hi/lo per-batch [1024][2048]
// =====================================================================
__global__ void transpose_v_k(const u16* __restrict__ vh, const u16* __restrict__ vl,
                              u16* __restrict__ vth, u16* __restrict__ vtl) {
    __shared__ u16 th[32][33];
    __shared__ u16 tl[32][33];
    int z = blockIdx.z;
    int d0 = blockIdx.x * 32, s0 = blockIdx.y * 32;
    int tx = threadIdx.x, ty = threadIdx.y;
#pragma unroll
    for (int r0 = 0; r0 < 4; ++r0) {
        int r = ty + r0 * 8;
        long idx = ((long)z * 2048 + s0 + r) * 1024 + d0 + tx;
        th[r][tx] = vh[idx];
        tl[r][tx] = vl[idx];
    }
    __syncthreads();
    long zoff = (long)z * 1024 * 2048;
#pragma unroll
    for (int r0 = 0; r0 < 4; ++r0) {
        int r = ty + r0 * 8;
        long idx = zoff + (long)(d0 + r) * 2048 + s0 + tx;
        vth[idx] = th[tx][r];
        vtl[idx] = tl[tx][r];
    }
}

// =====================================================================
// GEMM: C = A * B^T, 3-term bf16 hi/lo split (fp32-accurate).
// 512 threads = 8 waves (2 M-rows x 4 N-cols). Tile 128 x (NF*64).
// BK=32, 16x16x32 MFMA (R2 config: HW-verified 0 bank conflicts).
// XOR bank swizzle on 16B slots, applied via pre-swizzled global source
// (rule #21) and the matching ds_read address.
// MODE 0 (proj): ring-3 LDS (144KB, 1 block/CU), depth-2 prefetch,
//                counted vmcnt(6) across raw s_barrier — R2 schedule.
// MODE 1 (qk) / MODE 2 (pv): ring-2 LDS (64KB -> 2 blocks/CU for
//                cross-block bubble fill + 2x packing slots), depth-1
//                prefetch, vmcnt(0) at step top (loads are a full
//                compute-phase old -> cheap drain).
// MODE 1: causal block-skip (bj>bi), fp32 scores out.
// MODE 2: K limited to (bi+1)*4 steps; bi launch-reversed (LPT).
// =====================================================================
template <int MODE, int NF>
__launch_bounds__(512, 2)
__global__ void gemm_k(const u16* __restrict__ Ah, const u16* __restrict__ Al, long sAz,
                       const u16* __restrict__ Bh, const u16* __restrict__ Bl, long sBz,
                       int lda, int ldb, int Ksize,
                       float* __restrict__ outF, long sCz, int ldc,
                       u16* __restrict__ oh0, u16* __restrict__ oh1, u16* __restrict__ oh2,
                       u16* __restrict__ ol0, u16* __restrict__ ol1, u16* __restrict__ ol2,
                       const float* __restrict__ b0, const float* __restrict__ b1,
                       const float* __restrict__ b2) {
    constexpr int BN = NF * 64;
    constexpr int SLOT = 8192 + NF * 4096;   // u16 per ring slot (A hi/lo + B hi/lo)
    constexpr int RING = (MODE == 0) ? 3 : 2;
    __shared__ u16 lds[RING * SLOT];

    const int bi = (MODE == 2) ? (gridDim.x - 1 - (int)blockIdx.x) : blockIdx.x;
    const int bj = blockIdx.y, z = blockIdx.z;
    if (MODE == 1 && bj > bi) return;  // fully-masked causal block
    int nsteps = Ksize / 32;
    if (MODE == 2) nsteps = min(nsteps, (bi + 1) * 4);

    const u16* gA_h = Ah + (long)z * sAz;
    const u16* gA_l = Al + (long)z * sAz;
    const u16* gB_h = Bh + (long)z * sBz;
    const u16* gB_l = Bl + (long)z * sBz;

    const int tid = threadIdx.x;
    const int lane = tid & 63, w = tid >> 6;
    const int wr = w >> 2, wc = w & 3;

    // ---- staging per-thread global offsets (pre-swizzled source, rule #21) ----
    const int srow = tid >> 2;                                   // LDS row 0..127
    const int ls8 = (((tid & 3) ^ ((tid >> 3) & 3)) << 3);       // swizzled k-slot * 8
    const long aoff  = ((long)bi * 128 + srow) * lda + ls8;
    const long boff0 = ((long)bj * BN + srow) * ldb + ls8;
    const long boff1 = boff0 + 128L * (long)ldb;                 // NF==4 second chunk
    const int wbase = w * 512;                                   // u16, wave-uniform

    f32x4 acc[4][NF] = {};

    const int fr = lane & 15;
    const int ps8 = (((lane >> 4) ^ ((fr >> 1) & 3)) << 3);      // swizzled read slot * 8

    auto stage = [&](int slot, int step) {
        const int k0 = step * 32;
        u16* sb = lds + slot * SLOT;
        gld16(sb + wbase,              gA_h + aoff + k0);
        gld16(sb + 4096 + wbase,       gA_l + aoff + k0);
        gld16(sb + 8192 + wbase,       gB_h + boff0 + k0);
        if constexpr (NF == 4) gld16(sb + 12288 + wbase, gB_h + boff1 + k0);
        gld16(sb + 8192 + NF * 2048 + wbase, gB_l + boff0 + k0);
        if constexpr (NF == 4) gld16(sb + 8192 + NF * 2048 + 4096 + wbase, gB_l + boff1 + k0);
    };

    auto compute = [&](int slot) {
        const u16* LA = lds + slot * SLOT;
        const u16* LB = LA + 8192;
        short8 afh[4], afl[4], bfh[NF], bfl[NF];
#pragma unroll
        for (int m = 0; m < 4; ++m) {
            int off = (wr * 64 + m * 16 + fr) * 32 + ps8;
            afh[m] = *(const short8*)(LA + off);
            afl[m] = *(const short8*)(LA + 4096 + off);
        }
#pragma unroll
        for (int n = 0; n < NF; ++n) {
            int off = (wc * (NF * 16) + n * 16 + fr) * 32 + ps8;
            bfh[n] = *(const short8*)(LB + off);
            bfl[n] = *(const short8*)(LB + NF * 2048 + off);
        }
        __builtin_amdgcn_s_setprio(1);
#pragma unroll
        for (int m = 0; m < 4; ++m)
#pragma unroll
            for (int n = 0; n < NF; ++n) {
                acc[m][n] = __builtin_amdgcn_mfma_f32_16x16x32_bf16(afh[m], bfh[n], acc[m][n], 0, 0, 0);
                acc[m][n] = __builtin_amdgcn_mfma_f32_16x16x32_bf16(afh[m], bfl[n], acc[m][n], 0, 0, 0);
                acc[m][n] = __builtin_amdgcn_mfma_f32_16x16x32_bf16(afl[m], bfh[n], acc[m][n], 0, 0, 0);
            }
        __builtin_amdgcn_s_setprio(0);
    };

    if constexpr (MODE == 0) {
        // ---- ring-3, depth-2 prefetch, counted vmcnt (R2-proven) ----
        stage(0, 0);
        if (nsteps > 1) stage(1, 1);
        int cs = 0, ns = 2;
        for (int h = 0; h < nsteps; ++h) {
            if (h + 1 < nsteps) {
                asm volatile("s_waitcnt vmcnt(6)" ::: "memory");
            } else {
                asm volatile("s_waitcnt vmcnt(0)" ::: "memory");
            }
            __builtin_amdgcn_s_barrier();       // all waves' slot-cs loads landed
            __builtin_amdgcn_sched_barrier(0);  // don't hoist reads above the barrier
            if (h + 2 < nsteps) stage(ns, h + 2);  // slot (h-1)%3 consumed pre-barrier
            compute(cs);
            cs = (cs == 2) ? 0 : cs + 1;
            ns = (ns == 2) ? 0 : ns + 1;
        }
    } else {
        // ---- ring-2, depth-1 prefetch (2 blocks/CU fill the bubbles) ----
        stage(0, 0);
        int cs = 0;
        for (int h = 0; h < nsteps; ++h) {
            asm volatile("s_waitcnt vmcnt(0)" ::: "memory");  // slot-cs loads (issued
            __builtin_amdgcn_s_barrier();                     // one compute ago) landed
            __builtin_amdgcn_sched_barrier(0);
            if (h + 1 < nsteps) stage(cs ^ 1, h + 1);  // slot cs^1: read at h-1, barrier since
            compute(cs);
            cs ^= 1;
        }
    }

    // ---- epilogue: C/D layout col = lane&15, row = (lane>>4)*4 + j ----
    const int row0 = bi * 128 + wr * 64 + (lane >> 4) * 4;
    const int col0 = bj * BN + wc * (NF * 16) + (lane & 15);

    if (MODE == 0) {
        const float* bias = (z == 0) ? b0 : (z == 1) ? b1 : b2;
        u16* oh = (z == 0) ? oh0 : (z == 1) ? oh1 : oh2;
        u16* ol = (z == 0) ? ol0 : (z == 1) ? ol1 : ol2;
#pragma unroll
        for (int n = 0; n < NF; ++n) {
            float bv = bias[col0 + n * 16];
#pragma unroll
            for (int m = 0; m < 4; ++m)
#pragma unroll
                for (int j = 0; j < 4; ++j) {
                    float v = acc[m][n][j] + bv;
                    long idx = (long)(row0 + m * 16 + j) * ldc + col0 + n * 16;
                    u16 h = f2bf(v);
                    oh[idx] = h;
                    ol[idx] = f2bf(v - bf2f(h));
                }
        }
    } else {
        float* o = outF + (long)z * sCz;
#pragma unroll
        for (int m = 0; m < 4; ++m)
#pragma unroll
            for (int n = 0; n < NF; ++n)
#pragma unroll
                for (int j = 0; j < 4; ++j)
                    o[(long)(row0 + m * 16 + j) * ldc + col0 + n * 16] = acc[m][n][j];
    }
}

// =====================================================================
// softmax: per row i of S [batch][2048][2048]: read j<=i, scale 1/32,
// exp-normalize, write P hi/lo bf16 only for cols < ((i>>7)+1)*128
// (all that PV's K-limit ever reads; diag-block upper part zero-filled).
// =====================================================================
__global__ void softmax_k(const float* __restrict__ S, u16* __restrict__ Ph,
                          u16* __restrict__ Pl) {
    const long row = blockIdx.x;  // 0..8191
    const int i = (int)(row & 2047);
    const float* srow = S + row * 2048;
    u16* ph = Ph + row * 2048;
    u16* pl = Pl + row * 2048;
    const int t = threadIdx.x;
    const int limit = ((i >> 7) + 1) << 7;

    float v[8];
    float m = -1e30f;
#pragma unroll
    for (int j = 0; j < 8; ++j) {
        int c = j * 256 + t;
        float x = (c <= i) ? srow[c] : -1e30f;
        v[j] = x;
        m = fmaxf(m, x);
    }
#pragma unroll
    for (int off = 32; off; off >>= 1) m = fmaxf(m, __shfl_xor(m, off));
    __shared__ float redm[4], reds[4];
    if ((t & 63) == 0) redm[t >> 6] = m;
    __syncthreads();
    m = fmaxf(fmaxf(redm[0], redm[1]), fmaxf(redm[2], redm[3]));

    float p[8];
    float s = 0.f;
#pragma unroll
    for (int j = 0; j < 8; ++j) {
        int c = j * 256 + t;
        float e = (c <= i) ? __expf((v[j] - m) * 0.03125f) : 0.f;
        p[j] = e;
        s += e;
    }
#pragma unroll
    for (int off = 32; off; off >>= 1) s += __shfl_xor(s, off);
    if ((t & 63) == 0) reds[t >> 6] = s;
    __syncthreads();
    s = reds[0] + reds[1] + reds[2] + reds[3];
    const float inv = 1.f / s;
#pragma unroll
    for (int j = 0; j < 8; ++j) {
        int c = j * 256 + t;
        if (c < limit) {
            float o = p[j] * inv;
            u16 h = f2bf(o);
            ph[c] = h;
            pl[c] = f2bf(o - bf2f(h));
        }
    }
}

// =====================================================================
extern "C" void kernel_launch(void* const* d_in, const int* in_sizes, int n_in,
                              void* d_out, int out_size, void* d_ws, size_t ws_size,
                              hipStream_t stream) {
    const float* x  = (const float*)d_in[0];
    const float* Wq = (const float*)d_in[1];
    const float* bq = (const float*)d_in[2];
    const float* Wk = (const float*)d_in[3];
    const float* bk = (const float*)d_in[4];
    const float* Wv = (const float*)d_in[5];
    const float* bv = (const float*)d_in[6];
    float* out = (float*)d_out;
    char* ws = (char*)d_ws;
    const size_t MB = 1ull << 20;

    // region1 (64MB): [xs_hi xs_lo wt_hi wt_lo] during proj, then S
    u16* xs_hi = (u16*)(ws + 0 * MB);
    u16* xs_lo = (u16*)(ws + 16 * MB);
    u16* wt_hi = (u16*)(ws + 32 * MB);
    u16* wt_lo = (u16*)(ws + 38 * MB);
    float* S   = (float*)(ws + 0 * MB);  // 64MB, after proj complete
    // region2 (64MB): [q_hi q_lo k_hi k_lo] during qk, then [P_hi P_lo]
    u16* q_hi = (u16*)(ws + 64 * MB);
    u16* q_lo = (u16*)(ws + 80 * MB);
    u16* k_hi = (u16*)(ws + 96 * MB);
    u16* k_lo = (u16*)(ws + 112 * MB);
    u16* P_hi = (u16*)(ws + 64 * MB);  // 32MB, after qk complete
    u16* P_lo = (u16*)(ws + 96 * MB);  // 32MB
    // region3/4
    u16* v_hi  = (u16*)(ws + 128 * MB);
    u16* v_lo  = (u16*)(ws + 144 * MB);
    u16* vt_hi = (u16*)(ws + 160 * MB);
    u16* vt_lo = (u16*)(ws + 176 * MB);

    // 1) split x into bf16 hi/lo
    split_x_k<<<8192, 256, 0, stream>>>(x, xs_hi, xs_lo);
    // 2) transpose+split W -> Wt hi/lo ([3][1024][1024])
    splitT_w_k<<<dim3(32, 32, 3), dim3(32, 8), 0, stream>>>(Wq, Wk, Wv, wt_hi, wt_lo);
    // 3) QKV projections: [8192x1024] = x * Wt^T (+bias); tile 128x256, grid 768 = 3/CU
    gemm_k<0, 4><<<dim3(64, 4, 3), 512, 0, stream>>>(
        xs_hi, xs_lo, 0L, wt_hi, wt_lo, 1024L * 1024, 1024, 1024, 1024,
        nullptr, 0L, 1024, q_hi, k_hi, v_hi, q_lo, k_lo, v_lo, bq, bk, bv);
    // 4) transpose V per batch -> vt [1024][2048]
    transpose_v_k<<<dim3(32, 64, 4), dim3(32, 8), 0, stream>>>(v_hi, v_lo, vt_hi, vt_lo);
    // 5) scores S = Q * K^T per batch; tile 128x128, causal block-skip, 2 blocks/CU
    gemm_k<1, 2><<<dim3(16, 16, 4), 512, 0, stream>>>(
        q_hi, q_lo, 2048L * 1024, k_hi, k_lo, 2048L * 1024, 1024, 1024, 1024,
        S, 2048L * 2048, 2048, nullptr, nullptr, nullptr, nullptr, nullptr, nullptr,
        nullptr, nullptr, nullptr);
    // 6) causal softmax rows -> P hi/lo bf16 (zero-filled in diag block)
    softmax_k<<<8192, 256, 0, stream>>>(S, P_hi, P_lo);
    // 7) out = P * V per batch; tile 128x128, K-limited, LPT order, 2 blocks/CU
    gemm_k<2, 2><<<dim3(16, 8, 4), 512, 0, stream>>>(
        P_hi, P_lo, 2048L * 2048, vt_hi, vt_lo, 1024L * 2048, 2048, 2048, 2048,
        out, 2048L * 1024, 1024, nullptr, nullptr, nullptr, nullptr, nullptr, nullptr,
        nullptr, nullptr, nullptr);
}